// Round 9
// baseline (570.619 us; speedup 1.0000x reference)
//
#include <hip/hip_runtime.h>

// LSTMModel: 4-layer LSTM (H=50, IN=7, B=1024, T=512) + FC(50->25 relu ->1).
// R17 = R16 (never ran: infra failure) with one parity bug fixed on re-audit:
// L1's input must read XP[(k-1)%3] (h0(k-1), written by L0 at interval B of
// slot k-1), not XP[(k-2)%3]. All other parities re-verified against the
// invariant "writer at slot j -> parity j%3".
//
// Mechanism (fits R8-R15 evidence): R10's 2090cy tick = lockstep phases in
// series: read-burst ~880 (CU-serial DS pipe) -> MFMA ~310/SIMD -> UPD trans
// ~620/SIMD -> store/barrier ~280. Register file pins 4 waves/SIMD; R13
// proved flag de-phasing loses; R9 proved within-wave reorder does nothing.
// Fix: group E = layers {0,2}, O = layers {1,3}. Interval A: E does READ+MFMA
// (accs persist in regs), O does UPD+STORE of its previous slot. Interval B:
// roles swap. Every interval runs LDS+MFMA pipes (one group) AND VALU/trans
// (other group) simultaneously. Accs live across ONE barrier -- they are live
// MFMA->UPD anyway, so peak pressure ~unchanged.
//
// Schedule: layer l at slot k processes t = k - dl, dl = [0,1,3,4] (extra +1
// at the L1->L2 hop so L2's read postdates L1's store by a full interval).
// All buffers depth-3: writer at slot k -> parity k%3. Read parities
// (re-verified): L0 in XP[(k-1)%3]; L1 in XP[(k-1)%3] (FIXED); L2 in
// Hbuf0[(k-2)%3]; L3 in Hbuf1[(k-1)%3]; own-h always [(k-1)%3]; store [k%3].
// XP row = [x(t) 0..6 | 1.0 @7 | h0(t-1) 8..57] (L0 pairs h0(t)+x(t+1) into
// XP[t%3]). Hbuf const-1.0 @56 (bias col, stores write cols<50 only).
// Xstage 64-ring + 32-tick refill bursts (R10 verbatim). exp2 constants
// folded into weights/bias (R10). FC reads h3(511) from Hbuf[2][515%3=2].
// Main loop: 172 iterations x 3 slots (slots 0..515); epilogue for O's
// P2(515) (only L3 passes GUARD).

#define H 50
#define INSZ 7
#define TT 512
#define NL 4
#define FC1N 25
#define BPG 4
#define NBLK 256
#define NTHREADS 1024
#define HS 80        // row stride in halves (40 dw = 8 mod 32: <=2-way, free)
#define BIASL 56

typedef _Float16 half_t;
typedef __attribute__((ext_vector_type(8))) _Float16 half8_t;
typedef __attribute__((ext_vector_type(4))) float float4_t;

struct Params {
  const float* x;
  const float* Wih[NL];
  const float* Whh[NL];
  const float* bih[NL];
  const float* bhh[NL];
  const float* W1;
  const float* b1;
  const float* W2;
  const float* b2;
  float* out;
};

#define MFMA16(A, B, C) __builtin_amdgcn_mfma_f32_16x16x32_f16((A), (B), (C), 0, 0, 0)
#define EXP2F(x) __builtin_amdgcn_exp2f(x)
#define RCPF(x) __builtin_amdgcn_rcpf(x)

__global__ __launch_bounds__(NTHREADS, 4) void lstm_r17(Params p) {
  __shared__ __align__(16) half_t XP[3][BPG][HS];        // x|bias|h0 rows
  __shared__ __align__(16) half_t Hbuf[3][3][BPG][HS];   // h of L1..L3
  __shared__ __align__(16) half_t Xstage[64][BPG][8];    // raw-x ring
  __shared__ float fc1_buf[BPG][FC1N];

  const int tid = threadIdx.x;
  const int b0 = blockIdx.x * BPG;
  const int lane = tid & 63;
  const int quad = lane >> 4;
  const int col = lane & 15;
  const int glay = tid >> 8;                     // layer (4 waves each)
  const int wl = (((tid >> 6) & 3) + glay) & 3;  // M-chunk, SIMD-balanced
  const bool isE = ((glay & 1) == 0);            // group E = layers 0,2
  const int dl = glay + (glay >> 1);             // slot skew: 0,1,3,4

  // ---- A fragments (R10 verbatim): row r = wl*64 + t4*16 + col (r=4u+q),
  //      k = g*32 + quad*8 + j; rows pre-scaled by the gate's exp2 constant.
  half8_t afrag[4][4];
#pragma unroll
  for (int t4 = 0; t4 < 4; ++t4) {
#pragma unroll
    for (int g = 0; g < 4; ++g) {
      half8_t v;
#pragma unroll
      for (int j = 0; j < 8; ++j) {
        const int r = wl * 64 + t4 * 16 + col;
        const int u = r >> 2, q = r & 3;
        const int k = g * 32 + quad * 8 + j;
        float wv = 0.0f;
        if (u < H) {
          const int row = q * H + u;
          if (glay == 0) {           // K=64: x 0..6, bias 7, own-h 8..57
            if (k < INSZ) wv = p.Wih[0][row * INSZ + k];
            else if (k == 7) wv = p.bih[0][row] + p.bhh[0][row];
            else if (k >= 8 && k < 8 + H) wv = p.Whh[0][row * H + (k - 8)];
          } else if (glay == 1) {    // input from XP: bias 7, in-h 8..57
            if (k == 7) wv = p.bih[1][row] + p.bhh[1][row];
            else if (k >= 8 && k < 8 + H) wv = p.Wih[1][row * H + (k - 8)];
            else if (k >= 64 && k < 64 + H) wv = p.Whh[1][row * H + (k - 64)];
          } else {                   // in-h 0..49, bias 56, own-h 64..113
            if (k < H) wv = p.Wih[glay][row * H + k];
            else if (k == BIASL) wv = p.bih[glay][row] + p.bhh[glay][row];
            else if (k >= 64 && k < 64 + H) wv = p.Whh[glay][row * H + (k - 64)];
          }
          wv *= (q == 2) ? -2.885390082f : -1.442695041f;  // fold exp2 scale
        }
        v[j] = (half_t)wv;
      }
      afrag[t4][g] = v;
    }
  }

  // ---- init LDS ----
  {
    unsigned* xz = (unsigned*)XP;
    for (int i = tid; i < 3 * BPG * HS / 2; i += NTHREADS) xz[i] = 0u;
    unsigned* hz = (unsigned*)Hbuf;
    for (int i = tid; i < 3 * 3 * BPG * HS / 2; i += NTHREADS) hz[i] = 0u;
  }
  __syncthreads();
  if (tid < 12) {  // XP bias-1.0 at col 7, all 3 parities
    XP[tid >> 2][tid & 3][7] = (half_t)1.0f;
  } else if (tid < 12 + 36) {  // Hbuf const-1.0 at col 56, all parities
    const int i = tid - 12, l = i / 12, pr = (i >> 2) % 3, b = i & 3;
    Hbuf[l][pr][b][BIASL] = (half_t)1.0f;
  }
  // ring fill t=0..63 + x(0) into XP[2] (read by L0 at k=0: parity (0-1)%3)
  for (int i = tid; i < 64 * BPG * INSZ; i += NTHREADS) {
    const int t = i / (BPG * INSZ), rem = i % (BPG * INSZ);
    const int b = rem / INSZ, k = rem % INSZ;
    const half_t xh = (half_t)p.x[((size_t)(b0 + b) * TT + t) * INSZ + k];
    Xstage[t][b][k] = xh;
    if (t == 0) XP[2][b][k] = xh;
  }
  __syncthreads();

  // ---- per-lane roles ----
  const int bb = col & 3;
  const int tsel = col >> 2;
  const int uu = 16 * wl + 4 * tsel + quad;
  const bool updact = (uu < H);

  // pointer triples, literal-indexed (stay in registers)
  const half_t* inP[3];
  const half_t* ownP[3];
  half_t* stP[3];
#pragma unroll
  for (int ph = 0; ph < 3; ++ph) {
    if (glay == 0) {
      inP[ph] = &XP[(ph + 2) % 3][bb][quad * 8];     // (k-1)%3
      ownP[ph] = inP[ph];                            // unused
      stP[ph] = &XP[ph][bb][8 + uu];
    } else if (glay == 1) {
      inP[ph] = &XP[(ph + 2) % 3][bb][quad * 8];     // (k-1)%3  [FIXED]
      ownP[ph] = &Hbuf[0][(ph + 2) % 3][bb][quad * 8];
      stP[ph] = &Hbuf[0][ph][bb][uu];
    } else if (glay == 2) {
      inP[ph] = &Hbuf[0][(ph + 1) % 3][bb][quad * 8]; // (k-2)%3
      ownP[ph] = &Hbuf[1][(ph + 2) % 3][bb][quad * 8];
      stP[ph] = &Hbuf[1][ph][bb][uu];
    } else {
      inP[ph] = &Hbuf[1][(ph + 2) % 3][bb][quad * 8]; // (k-1)%3
      ownP[ph] = &Hbuf[2][(ph + 2) % 3][bb][quad * 8];
      stP[ph] = &Hbuf[2][ph][bb][uu];
    }
  }

  // x-copy + ring-refill role: layer-0 wl==3 wave (lightest: 2 MFMAs)
  const bool xwave = (glay == 0) && (wl == 3);
  const bool xcopy = xwave && (lane < BPG * INSZ);
  const int cb = lane / INSZ, ck = lane % INSZ;  // valid when xcopy
  const int rb = lane >> 5;                      // refill: batch pair
  const int rt = lane & 31;                      //         t offset

  float cst = 0.0f;
  const float4_t fzc = {0.0f, 0.0f, 0.0f, 0.0f};
  float4_t a0 = fzc, a1 = fzc, a2 = fzc, a3 = fzc;  // persist across barrier

#define GUARD(KK) ((unsigned)((KK) - dl) < (unsigned)TT)

  // PART1: LDS reads + MFMA cluster -> a0..a3 (held across the barrier)
#define P1BODY(PIN, POWN)                                                       \
  {                                                                             \
    const half8_t v0 = *(const half8_t*)(PIN);                                  \
    const half8_t v1 = *(const half8_t*)((PIN) + 32);                           \
    if (glay == 0) {                                                            \
      __builtin_amdgcn_s_setprio(1);                                            \
      if (wl != 3) {                                                            \
        a0 = MFMA16(afrag[0][0], v0, fzc); a1 = MFMA16(afrag[1][0], v0, fzc);   \
        a2 = MFMA16(afrag[2][0], v0, fzc); a3 = MFMA16(afrag[3][0], v0, fzc);   \
        a0 = MFMA16(afrag[0][1], v1, a0); a1 = MFMA16(afrag[1][1], v1, a1);     \
        a2 = MFMA16(afrag[2][1], v1, a2); a3 = MFMA16(afrag[3][1], v1, a3);     \
      } else {                                                                  \
        a0 = MFMA16(afrag[0][0], v0, fzc);                                      \
        a0 = MFMA16(afrag[0][1], v1, a0);                                       \
        a1 = a0; a2 = a0; a3 = a0;                                              \
      }                                                                         \
      __builtin_amdgcn_s_setprio(0);                                            \
    } else {                                                                    \
      const half8_t v2 = *(const half8_t*)(POWN);                               \
      const half8_t v3 = *(const half8_t*)((POWN) + 32);                        \
      __builtin_amdgcn_s_setprio(1);                                            \
      if (wl != 3) {                                                            \
        a0 = MFMA16(afrag[0][0], v0, fzc); a1 = MFMA16(afrag[1][0], v0, fzc);   \
        a2 = MFMA16(afrag[2][0], v0, fzc); a3 = MFMA16(afrag[3][0], v0, fzc);   \
        a0 = MFMA16(afrag[0][1], v1, a0); a1 = MFMA16(afrag[1][1], v1, a1);     \
        a2 = MFMA16(afrag[2][1], v1, a2); a3 = MFMA16(afrag[3][1], v1, a3);     \
        a0 = MFMA16(afrag[0][2], v2, a0); a1 = MFMA16(afrag[1][2], v2, a1);     \
        a2 = MFMA16(afrag[2][2], v2, a2); a3 = MFMA16(afrag[3][2], v2, a3);     \
        a0 = MFMA16(afrag[0][3], v3, a0); a1 = MFMA16(afrag[1][3], v3, a1);     \
        a2 = MFMA16(afrag[2][3], v3, a2); a3 = MFMA16(afrag[3][3], v3, a3);     \
      } else {                                                                  \
        a0 = MFMA16(afrag[0][0], v0, fzc);                                      \
        a0 = MFMA16(afrag[0][1], v1, a0);                                       \
        a0 = MFMA16(afrag[0][2], v2, a0);                                       \
        a0 = MFMA16(afrag[0][3], v3, a0);                                       \
        a1 = a0; a2 = a0; a3 = a0;                                              \
      }                                                                         \
      __builtin_amdgcn_s_setprio(0);                                            \
    }                                                                           \
  }

  // PART2: gate extract + update + h store (from persisted a0..a3)
#define P2BODY(PST)                                                             \
  if (updact) {                                                                 \
    const float4_t g01 = (col & 4) ? a1 : a0;                                   \
    const float4_t g23 = (col & 4) ? a3 : a2;                                   \
    const float4_t ga = (col & 8) ? g23 : g01;                                  \
    const float di = 1.0f + EXP2F(ga[0]);                                       \
    const float df = 1.0f + EXP2F(ga[1]);                                       \
    const float dg = 1.0f + EXP2F(ga[2]);                                       \
    const float dq = 1.0f + EXP2F(ga[3]);                                       \
    const float r1 = RCPF(di * df);                                             \
    const float r2 = RCPF(dg * dq);                                             \
    const float gi = r1 * df;                                                   \
    const float gf = r1 * di;                                                   \
    const float gg = 2.0f * (r2 * dq) - 1.0f;                                   \
    const float go = r2 * dg;                                                   \
    cst = gf * cst + gi * gg;                                                   \
    const float dc = 1.0f + EXP2F(-2.885390082f * cst);                         \
    const float h = go * (2.0f * RCPF(dc) - 1.0f);                              \
    *(PST) = (half_t)h;                                                         \
  }

#define REFILL(K_)                                                              \
  if (xwave && ((K_)&31) == 8 && (K_) < 480) {                                  \
    const int tb = ((K_) & ~31) + 32;                                           \
    _Pragma("unroll") for (int pp = 0; pp < 2; ++pp) {                          \
      const int b = rb + 2 * pp;                                                \
      const int t = tb + rt;                                                    \
      const float* src = &p.x[((size_t)(b0 + b) * TT + t) * INSZ];              \
      half_t* dst = &Xstage[t & 63][b][0];                                      \
      _Pragma("unroll") for (int kk = 0; kk < INSZ; ++kk)                       \
          dst[kk] = (half_t)src[kk];                                            \
    }                                                                           \
  }

  // One slot = interval A (E:P1(k) | O:P2(k-1)) + barrier +
  //            interval B (E:P2(k)+xcopy | O:P1(k)) + barrier.
#define SLOT(K_, PH)                                                            \
  {                                                                             \
    if (isE) {                                                                  \
      if (GUARD(K_)) P1BODY(inP[PH], ownP[PH])                                  \
    } else {                                                                    \
      if (GUARD((K_)-1)) P2BODY(stP[((PH) + 2) % 3])                            \
    }                                                                           \
    __syncthreads();                                                            \
    if (isE) {                                                                  \
      if (GUARD(K_)) {                                                          \
        REFILL(K_)                                                              \
        P2BODY(stP[PH])                                                         \
        if (xcopy && (K_) + 1 < TT)                                             \
          XP[PH][cb][ck] = Xstage[((K_) + 1) & 63][cb][ck];                     \
      }                                                                         \
    } else {                                                                    \
      if (GUARD(K_)) P1BODY(inP[PH], ownP[PH])                                  \
    }                                                                           \
    __syncthreads();                                                            \
  }

  // ---- main loop: slots k = 0..515 (516 = 3*172), 3-unrolled for parity ----
  for (int k = 0; k < 516; k += 3) {
    SLOT(k, 0)
    SLOT(k + 1, 1)
    SLOT(k + 2, 2)
  }
  // epilogue: O-group P2(515) (only L3 passes GUARD: t = 511)
  if (!isE && GUARD(515)) {
    P2BODY(stP[2])  // 515 % 3 = 2
  }
  __syncthreads();

  // ---- FC head (fp32); h3(511) is in Hbuf[2][2] cols 0..49 ----
  if (tid < BPG * FC1N) {
    const int b = tid / FC1N, j = tid % FC1N;
    const float* w = p.W1 + j * H;
    float a = p.b1[j];
#pragma unroll
    for (int k = 0; k < H; ++k) a += (float)Hbuf[2][2][b][k] * w[k];
    fc1_buf[b][j] = fmaxf(a, 0.0f);
  }
  __syncthreads();
  if (tid < BPG) {
    float a = p.b2[0];
#pragma unroll
    for (int j = 0; j < FC1N; ++j) a += fc1_buf[tid][j] * p.W2[j];
    p.out[b0 + tid] = a;
  }
}

extern "C" void kernel_launch(void* const* d_in, const int* in_sizes, int n_in,
                              void* d_out, int out_size, void* d_ws, size_t ws_size,
                              hipStream_t stream) {
  Params p;
  p.x = (const float*)d_in[0];
  for (int l = 0; l < NL; ++l) {
    p.Wih[l] = (const float*)d_in[1 + 4 * l];
    p.Whh[l] = (const float*)d_in[2 + 4 * l];
    p.bih[l] = (const float*)d_in[3 + 4 * l];
    p.bhh[l] = (const float*)d_in[4 + 4 * l];
  }
  p.W1 = (const float*)d_in[17];
  p.b1 = (const float*)d_in[18];
  p.W2 = (const float*)d_in[19];
  p.b2 = (const float*)d_in[20];
  p.out = (float*)d_out;

  hipLaunchKernelGGL(lstm_r17, dim3(NBLK), dim3(NTHREADS), 0, stream, p);
}